// Round 6
// baseline (317.179 us; speedup 1.0000x reference)
//
#include <hip/hip_runtime.h>

#define NM    4096
#define NPTS  131072
#define CAP   128

typedef _Float16 h2 __attribute__((ext_vector_type(2)));

#if __has_builtin(__builtin_amdgcn_fdot2)
#define FDOT2(a, b, c) __builtin_amdgcn_fdot2((a), (b), (c), false)
#else
static __device__ inline float FDOT2(h2 a, h2 b, float c) {
    return c + (float)a.x * (float)b.x + (float)a.y * (float)b.y;
}
#endif

#if __has_builtin(__builtin_amdgcn_global_load_lds)
#define USE_DMA 1
#else
#define USE_DMA 0
#endif

static __device__ inline h2 pk(float a, float b) {
    return __builtin_bit_cast(h2, __builtin_amdgcn_cvt_pkrtz(a, b));
}

// Skewed fp16 LDS layout (verified: bank conflicts -> 0 in R4):
// 2 half-blocks of 16 rows, +4 h2 (16B) skew between halves.
#define W0_HALF 516   // 16 rows * 32 h2 + 4
#define W1_HALF 260   // 16 rows * 16 h2 + 4

// h2-index offsets inside the single 12672 B buffer sH[3168]
#define H_W0 0        // 1032 h2 (bytes     0..4128)
#define H_VW 1032     // 1032 h2 (bytes  4128..8256)
#define H_W1 2064     //  520 h2 (bytes  8256..10336)
#define H_FW 2584     //  520 h2 (bytes 10336..12416)
#define H_SW 3104     //   16 h2
#define H_RW 3120     //   48 h2
#define H_TOT 3168    // 12672 B
// fp32 DMA scratch X overlays sH at float index 1032 (byte 4128):
//   w0 needs 2016 floats -> bytes [4128,12192) ; vw 1888 -> [4128,11680)
#define X_OFF 1032

#if USE_DMA
static __device__ inline void dma16(const float* g, const float* l) {
    __builtin_amdgcn_global_load_lds(
        (const __attribute__((address_space(1))) void*)g,
        (__attribute__((address_space(3))) void*)l, 16, 0, 0);
}
#endif

__global__ __launch_bounds__(256) void k_bucket(const float* __restrict__ pts,
                                                int* __restrict__ count,
                                                int* __restrict__ plist) {
    int n = blockIdx.x * 256 + threadIdx.x;
    if (n >= NPTS) return;
    float x = pts[3 * n + 0], y = pts[3 * n + 1], z = pts[3 * n + 2];
    int ix = (int)fminf(fmaxf(x * 16.f, 0.f), 15.f);
    int iy = (int)fminf(fmaxf(y * 16.f, 0.f), 15.f);
    int iz = (int)fminf(fmaxf(z * 16.f, 0.f), 15.f);
    int v = (ix << 8) | (iy << 4) | iz;
    int pos = atomicAdd(&count[v], 1);
    if (pos < CAP) plist[v * CAP + pos] = n;
}

__global__ __launch_bounds__(64, 3) void k_mlp(
    const float* __restrict__ pts, const float* __restrict__ vds,
    const float* __restrict__ w0g, const float* __restrict__ b0g,
    const float* __restrict__ w1g, const float* __restrict__ b1g,
    const float* __restrict__ fwg, const float* __restrict__ fbg,
    const float* __restrict__ swg, const float* __restrict__ sbg,
    const float* __restrict__ vwg, const float* __restrict__ vbg,
    const float* __restrict__ rwg, const float* __restrict__ rbg,
    const int* __restrict__ count, const int* __restrict__ plist,
    float* __restrict__ out) {
    __shared__ __align__(16) h2 sH[H_TOT];
    __shared__ float sB0[32], sB1[32], sFB[32], sVB[32], sRB[3], sSB[1];

    const int v = blockIdx.x;
    const int t = threadIdx.x;
    const int c = min(count[v], CAP);
    if (c == 0) return;

    float* X = (float*)sH + X_OFF;

    // ---- issue stage-1 DMA (w0, 2016 floats = 7x1024B + 896B) ----
#if USE_DMA
    {
        const float* g = w0g + (size_t)v * 2016;
        #pragma unroll
        for (int k = 0; k < 7; k++) dma16(g + k * 256 + t * 4, X + k * 256);
        if (t < 56) dma16(g + 1792 + t * 4, X + 1792);
    }
#endif
    // ---- issue register loads for row-aligned arrays (pipelined) ----
    float4 w1f[4], fwf[4], swf, rwf;
    {
        const float4* p = (const float4*)(w1g + (size_t)v * 1024);
        #pragma unroll
        for (int k = 0; k < 4; k++) w1f[k] = p[t + 64 * k];
        p = (const float4*)(fwg + (size_t)v * 1024);
        #pragma unroll
        for (int k = 0; k < 4; k++) fwf[k] = p[t + 64 * k];
        if (t < 8)  swf = ((const float4*)(swg + (size_t)v * 32))[t];
        if (t < 24) rwf = ((const float4*)(rwg + (size_t)v * 96))[t];
    }
    // biases (small)
    if (t < 32) {
        sB0[t] = b0g[v * 32 + t];
        sB1[t] = b1g[v * 32 + t];
        sFB[t] = fbg[v * 32 + t];
        sVB[t] = vbg[v * 32 + t];
    }
    if (t < 3) sRB[t] = rbg[v * 3 + t];
    if (t == 3) sSB[0] = sbg[v];

    // prefetch first iteration's point data (overlaps DMA drain)
    float pxc, pyc, pzc, dxc, dyc, dzc;
    int nc;
    {
        int sl = min(t >> 1, c - 1);
        nc = plist[v * CAP + sl];
        pxc = pts[3 * nc]; pyc = pts[3 * nc + 1]; pzc = pts[3 * nc + 2];
        int ray = nc >> 7;
        dxc = vds[3 * ray]; dyc = vds[3 * ray + 1]; dzc = vds[3 * ray + 2];
    }

    __syncthreads();   // drain stage-1 DMA + reg loads + bias writes

    // ---- stage-1 repack: w0 fp32 (X, bytes>=4128) -> sW0 (bytes <4128) ----
#if !USE_DMA
    // fallback: copy w0 into X via registers
    {
        const float* g = w0g + (size_t)v * 2016;
        for (int i = t; i < 2016; i += 64) X[i] = g[i];
        __syncthreads();
    }
#endif
    #pragma unroll
    for (int i = t; i < 1024; i += 64) {
        int r = i >> 5, j = i & 31;
        const float* rp = X + r * 63;
        float f0 = rp[2 * j];
        float f1 = (j < 31) ? rp[2 * j + 1] : 0.f;
        sH[H_W0 + (r >> 4) * W0_HALF + (r & 15) * 32 + j] = pk(f0, f1);
    }
    __syncthreads();   // stage-1 reads of X complete

    // ---- issue stage-2 DMA (vw, 1888 floats = 7x1024B + 384B) ----
#if USE_DMA
    {
        const float* g = vwg + (size_t)v * 1888;
        #pragma unroll
        for (int k = 0; k < 7; k++) dma16(g + k * 256 + t * 4, X + k * 256);
        if (t < 24) dma16(g + 1792 + t * 4, X + 1792);
    }
#endif
    __syncthreads();   // drain stage-2 DMA
#if !USE_DMA
    {
        const float* g = vwg + (size_t)v * 1888;
        for (int i = t; i < 1888; i += 64) X[i] = g[i];
        __syncthreads();
    }
#endif

    // ---- stage-2: register-stage vw pairs (dest overlaps X) ----
    h2 vreg[16];
    #pragma unroll
    for (int kk = 0; kk < 16; kk++) {
        int i = kk * 64 + t;
        int r = i >> 5, j = i & 31;
        const float* rp = X + r * 59;
        float f0 = (j < 30) ? rp[2 * j] : 0.f;
        float f1 = (j < 29) ? rp[2 * j + 1] : 0.f;
        vreg[kk] = pk(f0, f1);
    }
    __syncthreads();   // all vw reads complete; X is dead

    // write sVW from registers
    #pragma unroll
    for (int kk = 0; kk < 16; kk++) {
        int i = kk * 64 + t;
        int r = i >> 5, j = i & 31;
        sH[H_VW + (r >> 4) * W0_HALF + (r & 15) * 32 + j] = vreg[kk];
    }
    // write w1/fw/sw/rw from converted register loads
    #pragma unroll
    for (int k = 0; k < 4; k++) {
        int idx = t + 64 * k;
        int r = idx >> 3, jj = (idx & 7) * 2;
        h2* d = &sH[H_W1 + (r >> 4) * W1_HALF + (r & 15) * 16 + jj];
        d[0] = pk(w1f[k].x, w1f[k].y); d[1] = pk(w1f[k].z, w1f[k].w);
        d = &sH[H_FW + (r >> 4) * W1_HALF + (r & 15) * 16 + jj];
        d[0] = pk(fwf[k].x, fwf[k].y); d[1] = pk(fwf[k].z, fwf[k].w);
    }
    if (t < 8)  { sH[H_SW + 2 * t] = pk(swf.x, swf.y); sH[H_SW + 2 * t + 1] = pk(swf.z, swf.w); }
    if (t < 24) {
        int r = t >> 3, jj = (t & 7) * 2;
        sH[H_RW + r * 16 + jj] = pk(rwf.x, rwf.y);
        sH[H_RW + r * 16 + jj + 1] = pk(rwf.z, rwf.w);
    }
    __syncthreads();   // fp16 weights visible

    const h2* sW0 = sH + H_W0;
    const h2* sVW = sH + H_VW;
    const h2* sW1 = sH + H_W1;
    const h2* sFW = sH + H_FW;
    const h2* sSW = sH + H_SW;
    const h2* sRW = sH + H_RW;

    const int half = t & 1;          // 2 lanes per point: 16 rows each
    const int rb16 = half << 4;

    for (int base = 0; base < c; base += 32) {
        const int slot = base + (t >> 1);
        const bool active = slot < c;
        const int n = nc;
        const float px = pxc, py = pyc, pz = pzc;
        const float dx = dxc, dy = dyc, dz = dzc;

        // prefetch next iteration's gather (hides plist->pts chain)
        if (base + 32 < c) {
            int sl2 = min(base + 32 + (t >> 1), c - 1);
            nc = plist[v * CAP + sl2];
            pxc = pts[3 * nc]; pyc = pts[3 * nc + 1]; pzc = pts[3 * nc + 2];
            int ray2 = nc >> 7;
            dxc = vds[3 * ray2]; dyc = vds[3 * ray2 + 1]; dzc = vds[3 * ray2 + 2];
        }

        // ---- xyz encoding packed directly into h2 (carry chain) ----
        h2 eph[32];
        eph[0] = pk(px, py);
        {
            float carry = pz, f = 1.f;
            #pragma unroll
            for (int k = 0; k < 10; k++) {
                float s0 = __sinf(px * f), s1 = __sinf(py * f), s2 = __sinf(pz * f);
                float c0 = __cosf(px * f), c1 = __cosf(py * f), c2 = __cosf(pz * f);
                eph[1 + 3 * k] = pk(carry, s0);
                eph[2 + 3 * k] = pk(s1, s2);
                eph[3 + 3 * k] = pk(c0, c1);
                carry = c2;
                f *= 2.f;
            }
            eph[31] = pk(carry, 0.f);
        }

        // ---- layer 0 ----
        float h[16];
        #pragma unroll
        for (int o = 0; o < 16; o++) {
            const h2* wr = &sW0[half * W0_HALF + o * 32];
            float a0 = sB0[rb16 + o], a1 = 0.f;
            #pragma unroll
            for (int j = 0; j < 32; j += 2) {
                a0 = FDOT2(wr[j], eph[j], a0);
                a1 = FDOT2(wr[j + 1], eph[j + 1], a1);
            }
            h[o] = fmaxf(a0 + a1, 0.f);
        }
        h2 hh[16];
        {
            float ho[16];
            #pragma unroll
            for (int j = 0; j < 16; j++) ho[j] = __shfl_xor(h[j], 1, 64);
            #pragma unroll
            for (int j = 0; j < 8; j++) {
                hh[j]     = pk(half ? ho[2 * j] : h[2 * j],  half ? ho[2 * j + 1] : h[2 * j + 1]);
                hh[8 + j] = pk(half ? h[2 * j] : ho[2 * j],  half ? h[2 * j + 1] : ho[2 * j + 1]);
            }
        }

        // ---- layer 1 ----
        float g[16];
        #pragma unroll
        for (int o = 0; o < 16; o++) {
            const h2* wr = &sW1[half * W1_HALF + o * 16];
            float a0 = sB1[rb16 + o], a1 = 0.f;
            #pragma unroll
            for (int j = 0; j < 16; j += 2) {
                a0 = FDOT2(wr[j], hh[j], a0);
                a1 = FDOT2(wr[j + 1], hh[j + 1], a1);
            }
            g[o] = fmaxf(a0 + a1, 0.f);
        }
        h2 gh[16];
        {
            float go[16];
            #pragma unroll
            for (int j = 0; j < 16; j++) go[j] = __shfl_xor(g[j], 1, 64);
            #pragma unroll
            for (int j = 0; j < 8; j++) {
                gh[j]     = pk(half ? go[2 * j] : g[2 * j],  half ? go[2 * j + 1] : g[2 * j + 1]);
                gh[8 + j] = pk(half ? g[2 * j] : go[2 * j],  half ? g[2 * j + 1] : go[2 * j + 1]);
            }
        }

        // ---- sigma ----
        float sg;
        {
            float a0 = sSB[0], a1 = 0.f;
            #pragma unroll
            for (int j = 0; j < 16; j += 2) {
                a0 = FDOT2(sSW[j], gh[j], a0);
                a1 = FDOT2(sSW[j + 1], gh[j + 1], a1);
            }
            sg = a0 + a1;
        }

        // ---- feature layer (no relu) ----
        float ft[16];
        #pragma unroll
        for (int o = 0; o < 16; o++) {
            const h2* wr = &sFW[half * W1_HALF + o * 16];
            float a0 = sFB[rb16 + o], a1 = 0.f;
            #pragma unroll
            for (int j = 0; j < 16; j += 2) {
                a0 = FDOT2(wr[j], gh[j], a0);
                a1 = FDOT2(wr[j + 1], gh[j + 1], a1);
            }
            ft[o] = a0 + a1;
        }

        // ---- view input: feat(32) + dir encoding(27) + pad ----
        h2 hv[32];
        {
            float fo[16];
            #pragma unroll
            for (int j = 0; j < 16; j++) fo[j] = __shfl_xor(ft[j], 1, 64);
            #pragma unroll
            for (int j = 0; j < 8; j++) {
                hv[j]     = pk(half ? fo[2 * j] : ft[2 * j],  half ? fo[2 * j + 1] : ft[2 * j + 1]);
                hv[8 + j] = pk(half ? ft[2 * j] : fo[2 * j],  half ? ft[2 * j + 1] : fo[2 * j + 1]);
            }
            hv[16] = pk(dx, dy);
            float carry = dz, f = 1.f;
            #pragma unroll
            for (int k = 0; k < 4; k++) {
                float s0 = __sinf(dx * f), s1 = __sinf(dy * f), s2 = __sinf(dz * f);
                float c0 = __cosf(dx * f), c1 = __cosf(dy * f), c2 = __cosf(dz * f);
                hv[17 + 3 * k] = pk(carry, s0);
                hv[18 + 3 * k] = pk(s1, s2);
                hv[19 + 3 * k] = pk(c0, c1);
                carry = c2;
                f *= 2.f;
            }
            hv[29] = pk(carry, 0.f);
            hv[30] = pk(0.f, 0.f);
            hv[31] = pk(0.f, 0.f);
        }

        // ---- view layer ----
        float h3[16];
        #pragma unroll
        for (int o = 0; o < 16; o++) {
            const h2* wr = &sVW[half * W0_HALF + o * 32];
            float a0 = sVB[rb16 + o], a1 = 0.f;
            #pragma unroll
            for (int j = 0; j < 32; j += 2) {
                a0 = FDOT2(wr[j], hv[j], a0);
                a1 = FDOT2(wr[j + 1], hv[j + 1], a1);
            }
            h3[o] = fmaxf(a0 + a1, 0.f);
        }
        h2 h3h[16];
        {
            float ho[16];
            #pragma unroll
            for (int j = 0; j < 16; j++) ho[j] = __shfl_xor(h3[j], 1, 64);
            #pragma unroll
            for (int j = 0; j < 8; j++) {
                h3h[j]     = pk(half ? ho[2 * j] : h3[2 * j],  half ? ho[2 * j + 1] : h3[2 * j + 1]);
                h3h[8 + j] = pk(half ? h3[2 * j] : ho[2 * j],  half ? h3[2 * j + 1] : ho[2 * j + 1]);
            }
        }

        // ---- rgb ----
        float r0 = sRB[0], r1 = sRB[1], r2 = sRB[2];
        {
            float b0 = 0.f, b1 = 0.f, b2 = 0.f;
            #pragma unroll
            for (int j = 0; j < 16; j += 2) {
                r0 = FDOT2(sRW[j], h3h[j], r0);       b0 = FDOT2(sRW[j + 1], h3h[j + 1], b0);
                r1 = FDOT2(sRW[16 + j], h3h[j], r1);  b1 = FDOT2(sRW[16 + j + 1], h3h[j + 1], b1);
                r2 = FDOT2(sRW[32 + j], h3h[j], r2);  b2 = FDOT2(sRW[32 + j + 1], h3h[j + 1], b2);
            }
            r0 += b0; r1 += b1; r2 += b2;
        }

        if (active && half == 0) {
            out[3 * n + 0] = r0;
            out[3 * n + 1] = r1;
            out[3 * n + 2] = r2;
            out[3 * NPTS + n] = sg;
        }
    }
}

extern "C" void kernel_launch(void* const* d_in, const int* in_sizes, int n_in,
                              void* d_out, int out_size, void* d_ws, size_t ws_size,
                              hipStream_t stream) {
    const float* pts = (const float*)d_in[0];
    const float* vds = (const float*)d_in[1];
    const float* w0  = (const float*)d_in[2];
    const float* b0  = (const float*)d_in[3];
    const float* w1  = (const float*)d_in[4];
    const float* b1  = (const float*)d_in[5];
    const float* fw  = (const float*)d_in[6];
    const float* fb  = (const float*)d_in[7];
    const float* sw  = (const float*)d_in[8];
    const float* sb  = (const float*)d_in[9];
    const float* vw  = (const float*)d_in[10];
    const float* vb  = (const float*)d_in[11];
    const float* rw  = (const float*)d_in[12];
    const float* rb  = (const float*)d_in[13];
    float* out = (float*)d_out;

    int* count = (int*)d_ws;
    int* plist = (int*)((char*)d_ws + NM * sizeof(int));

    (void)hipMemsetAsync(count, 0, NM * sizeof(int), stream);
    k_bucket<<<NPTS / 256, 256, 0, stream>>>(pts, count, plist);
    k_mlp<<<NM, 64, 0, stream>>>(pts, vds, w0, b0, w1, b1, fw, fb, sw, sb,
                                 vw, vb, rw, rb, count, plist, out);
}

// Round 7
// 266.523 us; speedup vs baseline: 1.1901x; 1.1901x over previous
//
#include <hip/hip_runtime.h>

#define NM    4096
#define NPTS  131072
#define CAP   128

typedef _Float16 h2 __attribute__((ext_vector_type(2)));

#if __has_builtin(__builtin_amdgcn_fdot2)
#define FDOT2(a, b, c) __builtin_amdgcn_fdot2((a), (b), (c), false)
#else
static __device__ inline float FDOT2(h2 a, h2 b, float c) {
    return c + (float)a.x * (float)b.x + (float)a.y * (float)b.y;
}
#endif

#if __has_builtin(__builtin_amdgcn_global_load_lds)
#define USE_DMA 1
#else
#define USE_DMA 0
#endif

static __device__ inline h2 pk(float a, float b) {
    return __builtin_bit_cast(h2, __builtin_amdgcn_cvt_pkrtz(a, b));
}

// Skewed fp16 LDS layout (verified: bank conflicts -> 0 in R4):
// 2 half-blocks of 16 rows, +4 h2 (16B) skew between halves.
#define W0_HALF 516   // 16 rows * 32 h2 + 4
#define W1_HALF 260   // 16 rows * 16 h2 + 4

// h2-index offsets inside the single 12672 B buffer sH[3168]
#define H_W0 0        // 1032 h2 (bytes     0..4128)
#define H_VW 1032     // 1032 h2 (bytes  4128..8256)
#define H_W1 2064     //  520 h2 (bytes  8256..10336)
#define H_FW 2584     //  520 h2 (bytes 10336..12416)
#define H_SW 3104     //   16 h2
#define H_RW 3120     //   48 h2
#define H_TOT 3168    // 12672 B
// fp32 DMA scratch X overlays sH at float index 1032 (byte 4128):
//   w0 needs 2016 floats -> bytes [4128,12192) ; vw 1888 -> [4128,11680)
#define X_OFF 1032

#if USE_DMA
static __device__ inline void dma16(const float* g, const float* l) {
    __builtin_amdgcn_global_load_lds(
        (const __attribute__((address_space(1))) void*)g,
        (__attribute__((address_space(3))) void*)l, 16, 0, 0);
}
#endif

__global__ __launch_bounds__(256) void k_bucket(const float* __restrict__ pts,
                                                int* __restrict__ count,
                                                int* __restrict__ plist) {
    int n = blockIdx.x * 256 + threadIdx.x;
    if (n >= NPTS) return;
    float x = pts[3 * n + 0], y = pts[3 * n + 1], z = pts[3 * n + 2];
    int ix = (int)fminf(fmaxf(x * 16.f, 0.f), 15.f);
    int iy = (int)fminf(fmaxf(y * 16.f, 0.f), 15.f);
    int iz = (int)fminf(fmaxf(z * 16.f, 0.f), 15.f);
    int v = (ix << 8) | (iy << 4) | iz;
    int pos = atomicAdd(&count[v], 1);
    if (pos < CAP) plist[v * CAP + pos] = n;
}

// NOTE: plain __launch_bounds__(64). R6's (64,3) forced VGPR 200->84 and the
// compiler spilled the hot loop to scratch: 254 MB HBM writes/dispatch, 1.6x
// slower. The loop needs ~200 VGPR; LDS (13.3 KB) and VGPR (2 waves/SIMD)
// then cap residency at 8 waves/CU.
__global__ __launch_bounds__(64) void k_mlp(
    const float* __restrict__ pts, const float* __restrict__ vds,
    const float* __restrict__ w0g, const float* __restrict__ b0g,
    const float* __restrict__ w1g, const float* __restrict__ b1g,
    const float* __restrict__ fwg, const float* __restrict__ fbg,
    const float* __restrict__ swg, const float* __restrict__ sbg,
    const float* __restrict__ vwg, const float* __restrict__ vbg,
    const float* __restrict__ rwg, const float* __restrict__ rbg,
    const int* __restrict__ count, const int* __restrict__ plist,
    float* __restrict__ out) {
    __shared__ __align__(16) h2 sH[H_TOT];
    __shared__ float sB0[32], sB1[32], sFB[32], sVB[32], sRB[3], sSB[1];

    const int v = blockIdx.x;
    const int t = threadIdx.x;
    const int c = min(count[v], CAP);
    if (c == 0) return;

    float* X = (float*)sH + X_OFF;

    // ---- issue stage-1 DMA (w0, 2016 floats = 7x1024B + 896B) ----
#if USE_DMA
    {
        const float* g = w0g + (size_t)v * 2016;
        #pragma unroll
        for (int k = 0; k < 7; k++) dma16(g + k * 256 + t * 4, X + k * 256);
        if (t < 56) dma16(g + 1792 + t * 4, X + 1792);
    }
#endif
    // ---- issue register loads for row-aligned arrays (pipelined) ----
    float4 w1f[4], fwf[4], swf, rwf;
    {
        const float4* p = (const float4*)(w1g + (size_t)v * 1024);
        #pragma unroll
        for (int k = 0; k < 4; k++) w1f[k] = p[t + 64 * k];
        p = (const float4*)(fwg + (size_t)v * 1024);
        #pragma unroll
        for (int k = 0; k < 4; k++) fwf[k] = p[t + 64 * k];
        if (t < 8)  swf = ((const float4*)(swg + (size_t)v * 32))[t];
        if (t < 24) rwf = ((const float4*)(rwg + (size_t)v * 96))[t];
    }
    // biases (small)
    if (t < 32) {
        sB0[t] = b0g[v * 32 + t];
        sB1[t] = b1g[v * 32 + t];
        sFB[t] = fbg[v * 32 + t];
        sVB[t] = vbg[v * 32 + t];
    }
    if (t < 3) sRB[t] = rbg[v * 3 + t];
    if (t == 3) sSB[0] = sbg[v];

    // prefetch first iteration's point data (overlaps DMA drain)
    float pxc, pyc, pzc, dxc, dyc, dzc;
    int nc;
    {
        int sl = min(t >> 1, c - 1);
        nc = plist[v * CAP + sl];
        pxc = pts[3 * nc]; pyc = pts[3 * nc + 1]; pzc = pts[3 * nc + 2];
        int ray = nc >> 7;
        dxc = vds[3 * ray]; dyc = vds[3 * ray + 1]; dzc = vds[3 * ray + 2];
    }

    __syncthreads();   // drain stage-1 DMA + reg loads + bias writes

    // ---- stage-1 repack: w0 fp32 (X, bytes>=4128) -> sW0 (bytes <4128) ----
#if !USE_DMA
    {
        const float* g = w0g + (size_t)v * 2016;
        for (int i = t; i < 2016; i += 64) X[i] = g[i];
        __syncthreads();
    }
#endif
    #pragma unroll
    for (int i = t; i < 1024; i += 64) {
        int r = i >> 5, j = i & 31;
        const float* rp = X + r * 63;
        float f0 = rp[2 * j];
        float f1 = (j < 31) ? rp[2 * j + 1] : 0.f;
        sH[H_W0 + (r >> 4) * W0_HALF + (r & 15) * 32 + j] = pk(f0, f1);
    }
    __syncthreads();   // stage-1 reads of X complete

    // ---- issue stage-2 DMA (vw, 1888 floats = 7x1024B + 384B) ----
#if USE_DMA
    {
        const float* g = vwg + (size_t)v * 1888;
        #pragma unroll
        for (int k = 0; k < 7; k++) dma16(g + k * 256 + t * 4, X + k * 256);
        if (t < 24) dma16(g + 1792 + t * 4, X + 1792);
    }
#endif
    __syncthreads();   // drain stage-2 DMA
#if !USE_DMA
    {
        const float* g = vwg + (size_t)v * 1888;
        for (int i = t; i < 1888; i += 64) X[i] = g[i];
        __syncthreads();
    }
#endif

    // ---- stage-2: register-stage vw pairs (dest overlaps X) ----
    h2 vreg[16];
    #pragma unroll
    for (int kk = 0; kk < 16; kk++) {
        int i = kk * 64 + t;
        int r = i >> 5, j = i & 31;
        const float* rp = X + r * 59;
        float f0 = (j < 30) ? rp[2 * j] : 0.f;
        float f1 = (j < 29) ? rp[2 * j + 1] : 0.f;
        vreg[kk] = pk(f0, f1);
    }
    __syncthreads();   // all vw reads complete; X is dead

    // write sVW from registers
    #pragma unroll
    for (int kk = 0; kk < 16; kk++) {
        int i = kk * 64 + t;
        int r = i >> 5, j = i & 31;
        sH[H_VW + (r >> 4) * W0_HALF + (r & 15) * 32 + j] = vreg[kk];
    }
    // write w1/fw/sw/rw from converted register loads
    #pragma unroll
    for (int k = 0; k < 4; k++) {
        int idx = t + 64 * k;
        int r = idx >> 3, jj = (idx & 7) * 2;
        h2* d = &sH[H_W1 + (r >> 4) * W1_HALF + (r & 15) * 16 + jj];
        d[0] = pk(w1f[k].x, w1f[k].y); d[1] = pk(w1f[k].z, w1f[k].w);
        d = &sH[H_FW + (r >> 4) * W1_HALF + (r & 15) * 16 + jj];
        d[0] = pk(fwf[k].x, fwf[k].y); d[1] = pk(fwf[k].z, fwf[k].w);
    }
    if (t < 8)  { sH[H_SW + 2 * t] = pk(swf.x, swf.y); sH[H_SW + 2 * t + 1] = pk(swf.z, swf.w); }
    if (t < 24) {
        int r = t >> 3, jj = (t & 7) * 2;
        sH[H_RW + r * 16 + jj] = pk(rwf.x, rwf.y);
        sH[H_RW + r * 16 + jj + 1] = pk(rwf.z, rwf.w);
    }
    __syncthreads();   // fp16 weights visible

    const h2* sW0 = sH + H_W0;
    const h2* sVW = sH + H_VW;
    const h2* sW1 = sH + H_W1;
    const h2* sFW = sH + H_FW;
    const h2* sSW = sH + H_SW;
    const h2* sRW = sH + H_RW;

    const int half = t & 1;          // 2 lanes per point: 16 rows each
    const int rb16 = half << 4;

    for (int base = 0; base < c; base += 32) {
        const int slot = base + (t >> 1);
        const bool active = slot < c;
        const int n = nc;
        const float px = pxc, py = pyc, pz = pzc;
        const float dx = dxc, dy = dyc, dz = dzc;

        // prefetch next iteration's gather (hides plist->pts chain)
        if (base + 32 < c) {
            int sl2 = min(base + 32 + (t >> 1), c - 1);
            nc = plist[v * CAP + sl2];
            pxc = pts[3 * nc]; pyc = pts[3 * nc + 1]; pzc = pts[3 * nc + 2];
            int ray2 = nc >> 7;
            dxc = vds[3 * ray2]; dyc = vds[3 * ray2 + 1]; dzc = vds[3 * ray2 + 2];
        }

        // ---- xyz encoding packed directly into h2 (carry chain) ----
        h2 eph[32];
        eph[0] = pk(px, py);
        {
            float carry = pz, f = 1.f;
            #pragma unroll
            for (int k = 0; k < 10; k++) {
                float s0 = __sinf(px * f), s1 = __sinf(py * f), s2 = __sinf(pz * f);
                float c0 = __cosf(px * f), c1 = __cosf(py * f), c2 = __cosf(pz * f);
                eph[1 + 3 * k] = pk(carry, s0);
                eph[2 + 3 * k] = pk(s1, s2);
                eph[3 + 3 * k] = pk(c0, c1);
                carry = c2;
                f *= 2.f;
            }
            eph[31] = pk(carry, 0.f);
        }

        // ---- layer 0 ----
        float h[16];
        #pragma unroll
        for (int o = 0; o < 16; o++) {
            const h2* wr = &sW0[half * W0_HALF + o * 32];
            float a0 = sB0[rb16 + o], a1 = 0.f;
            #pragma unroll
            for (int j = 0; j < 32; j += 2) {
                a0 = FDOT2(wr[j], eph[j], a0);
                a1 = FDOT2(wr[j + 1], eph[j + 1], a1);
            }
            h[o] = fmaxf(a0 + a1, 0.f);
        }
        h2 hh[16];
        {
            float ho[16];
            #pragma unroll
            for (int j = 0; j < 16; j++) ho[j] = __shfl_xor(h[j], 1, 64);
            #pragma unroll
            for (int j = 0; j < 8; j++) {
                hh[j]     = pk(half ? ho[2 * j] : h[2 * j],  half ? ho[2 * j + 1] : h[2 * j + 1]);
                hh[8 + j] = pk(half ? h[2 * j] : ho[2 * j],  half ? h[2 * j + 1] : ho[2 * j + 1]);
            }
        }

        // ---- layer 1 ----
        float g[16];
        #pragma unroll
        for (int o = 0; o < 16; o++) {
            const h2* wr = &sW1[half * W1_HALF + o * 16];
            float a0 = sB1[rb16 + o], a1 = 0.f;
            #pragma unroll
            for (int j = 0; j < 16; j += 2) {
                a0 = FDOT2(wr[j], hh[j], a0);
                a1 = FDOT2(wr[j + 1], hh[j + 1], a1);
            }
            g[o] = fmaxf(a0 + a1, 0.f);
        }
        h2 gh[16];
        {
            float go[16];
            #pragma unroll
            for (int j = 0; j < 16; j++) go[j] = __shfl_xor(g[j], 1, 64);
            #pragma unroll
            for (int j = 0; j < 8; j++) {
                gh[j]     = pk(half ? go[2 * j] : g[2 * j],  half ? go[2 * j + 1] : g[2 * j + 1]);
                gh[8 + j] = pk(half ? g[2 * j] : go[2 * j],  half ? g[2 * j + 1] : go[2 * j + 1]);
            }
        }

        // ---- sigma ----
        float sg;
        {
            float a0 = sSB[0], a1 = 0.f;
            #pragma unroll
            for (int j = 0; j < 16; j += 2) {
                a0 = FDOT2(sSW[j], gh[j], a0);
                a1 = FDOT2(sSW[j + 1], gh[j + 1], a1);
            }
            sg = a0 + a1;
        }

        // ---- feature layer (no relu) ----
        float ft[16];
        #pragma unroll
        for (int o = 0; o < 16; o++) {
            const h2* wr = &sFW[half * W1_HALF + o * 16];
            float a0 = sFB[rb16 + o], a1 = 0.f;
            #pragma unroll
            for (int j = 0; j < 16; j += 2) {
                a0 = FDOT2(wr[j], gh[j], a0);
                a1 = FDOT2(wr[j + 1], gh[j + 1], a1);
            }
            ft[o] = a0 + a1;
        }

        // ---- view input: feat(32) + dir encoding(27) + pad ----
        h2 hv[32];
        {
            float fo[16];
            #pragma unroll
            for (int j = 0; j < 16; j++) fo[j] = __shfl_xor(ft[j], 1, 64);
            #pragma unroll
            for (int j = 0; j < 8; j++) {
                hv[j]     = pk(half ? fo[2 * j] : ft[2 * j],  half ? fo[2 * j + 1] : ft[2 * j + 1]);
                hv[8 + j] = pk(half ? ft[2 * j] : fo[2 * j],  half ? ft[2 * j + 1] : fo[2 * j + 1]);
            }
            hv[16] = pk(dx, dy);
            float carry = dz, f = 1.f;
            #pragma unroll
            for (int k = 0; k < 4; k++) {
                float s0 = __sinf(dx * f), s1 = __sinf(dy * f), s2 = __sinf(dz * f);
                float c0 = __cosf(dx * f), c1 = __cosf(dy * f), c2 = __cosf(dz * f);
                hv[17 + 3 * k] = pk(carry, s0);
                hv[18 + 3 * k] = pk(s1, s2);
                hv[19 + 3 * k] = pk(c0, c1);
                carry = c2;
                f *= 2.f;
            }
            hv[29] = pk(carry, 0.f);
            hv[30] = pk(0.f, 0.f);
            hv[31] = pk(0.f, 0.f);
        }

        // ---- view layer ----
        float h3[16];
        #pragma unroll
        for (int o = 0; o < 16; o++) {
            const h2* wr = &sVW[half * W0_HALF + o * 32];
            float a0 = sVB[rb16 + o], a1 = 0.f;
            #pragma unroll
            for (int j = 0; j < 32; j += 2) {
                a0 = FDOT2(wr[j], hv[j], a0);
                a1 = FDOT2(wr[j + 1], hv[j + 1], a1);
            }
            h3[o] = fmaxf(a0 + a1, 0.f);
        }
        h2 h3h[16];
        {
            float ho[16];
            #pragma unroll
            for (int j = 0; j < 16; j++) ho[j] = __shfl_xor(h3[j], 1, 64);
            #pragma unroll
            for (int j = 0; j < 8; j++) {
                h3h[j]     = pk(half ? ho[2 * j] : h3[2 * j],  half ? ho[2 * j + 1] : h3[2 * j + 1]);
                h3h[8 + j] = pk(half ? h3[2 * j] : ho[2 * j],  half ? h3[2 * j + 1] : ho[2 * j + 1]);
            }
        }

        // ---- rgb ----
        float r0 = sRB[0], r1 = sRB[1], r2 = sRB[2];
        {
            float b0 = 0.f, b1 = 0.f, b2 = 0.f;
            #pragma unroll
            for (int j = 0; j < 16; j += 2) {
                r0 = FDOT2(sRW[j], h3h[j], r0);       b0 = FDOT2(sRW[j + 1], h3h[j + 1], b0);
                r1 = FDOT2(sRW[16 + j], h3h[j], r1);  b1 = FDOT2(sRW[16 + j + 1], h3h[j + 1], b1);
                r2 = FDOT2(sRW[32 + j], h3h[j], r2);  b2 = FDOT2(sRW[32 + j + 1], h3h[j + 1], b2);
            }
            r0 += b0; r1 += b1; r2 += b2;
        }

        if (active && half == 0) {
            out[3 * n + 0] = r0;
            out[3 * n + 1] = r1;
            out[3 * n + 2] = r2;
            out[3 * NPTS + n] = sg;
        }
    }
}

extern "C" void kernel_launch(void* const* d_in, const int* in_sizes, int n_in,
                              void* d_out, int out_size, void* d_ws, size_t ws_size,
                              hipStream_t stream) {
    const float* pts = (const float*)d_in[0];
    const float* vds = (const float*)d_in[1];
    const float* w0  = (const float*)d_in[2];
    const float* b0  = (const float*)d_in[3];
    const float* w1  = (const float*)d_in[4];
    const float* b1  = (const float*)d_in[5];
    const float* fw  = (const float*)d_in[6];
    const float* fb  = (const float*)d_in[7];
    const float* sw  = (const float*)d_in[8];
    const float* sb  = (const float*)d_in[9];
    const float* vw  = (const float*)d_in[10];
    const float* vb  = (const float*)d_in[11];
    const float* rw  = (const float*)d_in[12];
    const float* rb  = (const float*)d_in[13];
    float* out = (float*)d_out;

    int* count = (int*)d_ws;
    int* plist = (int*)((char*)d_ws + NM * sizeof(int));

    (void)hipMemsetAsync(count, 0, NM * sizeof(int), stream);
    k_bucket<<<NPTS / 256, 256, 0, stream>>>(pts, count, plist);
    k_mlp<<<NM, 64, 0, stream>>>(pts, vds, w0, b0, w1, b1, fw, fb, sw, sb,
                                 vw, vb, rw, rb, count, plist, out);
}

// Round 8
// 182.871 us; speedup vs baseline: 1.7344x; 1.4574x over previous
//
#include <hip/hip_runtime.h>

#define NM    4096
#define NPTS  131072
#define CAP   128

typedef _Float16 h8 __attribute__((ext_vector_type(8)));
typedef _Float16 h2 __attribute__((ext_vector_type(2)));
typedef float    f4 __attribute__((ext_vector_type(4)));
typedef int      i4 __attribute__((ext_vector_type(4)));

#define MF(a, b, c) __builtin_amdgcn_mfma_f32_16x16x32_f16((a), (b), (c), 0, 0, 0)

static __device__ inline h2 pk(float a, float b) {
    return __builtin_bit_cast(h2, __builtin_amdgcn_cvt_pkrtz(a, b));
}

static __device__ inline h8 pack8(float u0, float u1, float u2, float u3,
                                  float u4, float u5, float u6, float u7) {
    i4 t;
    t[0] = __builtin_bit_cast(int, pk(u0, u1));
    t[1] = __builtin_bit_cast(int, pk(u2, u3));
    t[2] = __builtin_bit_cast(int, pk(u4, u5));
    t[3] = __builtin_bit_cast(int, pk(u6, u7));
    return __builtin_bit_cast(h8, t);
}

// 8 guarded f16 from a weight row: dims d0..d0+7, zero past lim.
static __device__ inline h8 load_row8(const float* __restrict__ rb, int d0, int lim) {
    float u[8];
    #pragma unroll
    for (int jj = 0; jj < 8; jj++) {
        int d = d0 + jj;
        u[jj] = (d < lim) ? rb[d] : 0.f;
    }
    return pack8(u[0], u[1], u[2], u[3], u[4], u[5], u[6], u[7]);
}

// NeRF frequency-encoding dim d of 3-vector (x,y,z); 0 for d >= lim.
// Layout: [x,y,z, then per freq k: sin(x f),sin(y f),sin(z f),cos(x f),cos(y f),cos(z f)]
static __device__ inline float encdim(int d, int lim, float x, float y, float z) {
    int tt = d - 3;
    int k  = tt / 6;              // freq index (d<3 gives harmless garbage)
    int r  = tt - 6 * k;
    float p = x;
    p = (r == 1 || r == 4) ? y : p;
    p = (r == 2 || r == 5) ? z : p;
    float f   = __int_as_float((k + 127) << 23);   // 2^k
    float arg = p * f + ((r >= 3) ? 1.57079632679f : 0.f);  // cos = sin(+pi/2)
    float sv  = __sinf(arg);
    float raw = (d == 0) ? x : ((d == 1) ? y : z);
    float val = (d < 3) ? raw : sv;
    return (d < lim) ? val : 0.f;
}

// D-frag pair (rows 0-15 in d0, 16-31 in d1; row=quad*4+reg, col=lane&15)
// -> B-frag (k=quad*8+j, col=lane&15). Dest lane (q,c) takes:
//   j=0..3 from src lane ((q&1)*2)*16+c regs j, j=4..7 from +16, tile = q>>1.
// Both tiles must be shuffled (src lane doesn't know dest's tile need).
static __device__ inline h8 makeB(f4 d0, f4 d1, int quad, int col) {
    int laneA = ((quad & 1) * 2) * 16 + col;
    int laneB = laneA + 16;
    float a0 = __shfl(d0[0], laneA), b0 = __shfl(d1[0], laneA);
    float a1 = __shfl(d0[1], laneA), b1 = __shfl(d1[1], laneA);
    float a2 = __shfl(d0[2], laneA), b2 = __shfl(d1[2], laneA);
    float a3 = __shfl(d0[3], laneA), b3 = __shfl(d1[3], laneA);
    float a4 = __shfl(d0[0], laneB), b4 = __shfl(d1[0], laneB);
    float a5 = __shfl(d0[1], laneB), b5 = __shfl(d1[1], laneB);
    float a6 = __shfl(d0[2], laneB), b6 = __shfl(d1[2], laneB);
    float a7 = __shfl(d0[3], laneB), b7 = __shfl(d1[3], laneB);
    bool hi = quad >= 2;
    return pack8(hi ? b0 : a0, hi ? b1 : a1, hi ? b2 : a2, hi ? b3 : a3,
                 hi ? b4 : a4, hi ? b5 : a5, hi ? b6 : a6, hi ? b7 : a7);
}

static __device__ inline f4 relu4(f4 a) {
    f4 r;
    r[0] = fmaxf(a[0], 0.f); r[1] = fmaxf(a[1], 0.f);
    r[2] = fmaxf(a[2], 0.f); r[3] = fmaxf(a[3], 0.f);
    return r;
}

__global__ __launch_bounds__(256) void k_bucket(const float* __restrict__ pts,
                                                int* __restrict__ count,
                                                int* __restrict__ plist) {
    int n = blockIdx.x * 256 + threadIdx.x;
    if (n >= NPTS) return;
    float x = pts[3 * n + 0], y = pts[3 * n + 1], z = pts[3 * n + 2];
    int ix = (int)fminf(fmaxf(x * 16.f, 0.f), 15.f);
    int iy = (int)fminf(fmaxf(y * 16.f, 0.f), 15.f);
    int iz = (int)fminf(fmaxf(z * 16.f, 0.f), 15.f);
    int v = (ix << 8) | (iy << 4) | iz;
    int pos = atomicAdd(&count[v], 1);
    if (pos < CAP) plist[v * CAP + pos] = n;
}

// MFMA dataflow: weights live in VGPRs as A-fragments (loaded once/block from
// global; no LDS, no barriers). 16 points/iter = MFMA columns. NOTE: plain
// __launch_bounds__(64) — forcing min-waves spilled to scratch in R6 (254 MB
// HBM writes). Fragment layouts per cdna4 docs:
//   A[m=lane&15][k=quad*8+j], B[k=quad*8+j][n=lane&15], C/D row=quad*4+reg,
//   col=lane&15.
__global__ __launch_bounds__(64) void k_mlp(
    const float* __restrict__ pts, const float* __restrict__ vds,
    const float* __restrict__ w0g, const float* __restrict__ b0g,
    const float* __restrict__ w1g, const float* __restrict__ b1g,
    const float* __restrict__ fwg, const float* __restrict__ fbg,
    const float* __restrict__ swg, const float* __restrict__ sbg,
    const float* __restrict__ vwg, const float* __restrict__ vbg,
    const float* __restrict__ rwg, const float* __restrict__ rbg,
    const int* __restrict__ count, const int* __restrict__ plist,
    float* __restrict__ out) {
    const int v = blockIdx.x;
    const int t = threadIdx.x;
    const int c = min(count[v], CAP);
    if (c == 0) return;

    const int col  = t & 15;     // A-row index / point column / D column
    const int quad = t >> 4;
    const int k8   = quad * 8;

    // ---- first-iteration point prefetch (in flight during weight loads) ----
    float pxc, pyc, pzc, dxc, dyc, dzc;
    int ncur;
    {
        int sl = min(col, c - 1);
        ncur = plist[v * CAP + sl];
        pxc = pts[3 * ncur]; pyc = pts[3 * ncur + 1]; pzc = pts[3 * ncur + 2];
        int ray = ncur >> 7;
        dxc = vds[3 * ray]; dyc = vds[3 * ray + 1]; dzc = vds[3 * ray + 2];
    }

    // ---- weight A-fragments: global -> VGPR, once per block ----
    h8 aW0[2][2], aVW[2][2], aW1[2], aFW[2];
    #pragma unroll
    for (int Ti = 0; Ti < 2; Ti++) {
        const float* rb = w0g + (size_t)v * 2016 + (Ti * 16 + col) * 63;
        aW0[Ti][0] = load_row8(rb, k8, 63);
        aW0[Ti][1] = load_row8(rb, 32 + k8, 63);
        rb = vwg + (size_t)v * 1888 + (Ti * 16 + col) * 59;
        aVW[Ti][0] = load_row8(rb, k8, 59);
        aVW[Ti][1] = load_row8(rb, 32 + k8, 59);
        rb = w1g + (size_t)v * 1024 + (Ti * 16 + col) * 32;
        aW1[Ti] = load_row8(rb, k8, 32);
        rb = fwg + (size_t)v * 1024 + (Ti * 16 + col) * 32;
        aFW[Ti] = load_row8(rb, k8, 32);
    }
    h8 aSG = {};   // row 0 = sigma_w
    if (col == 0) aSG = load_row8(swg + (size_t)v * 32, k8, 32);
    h8 aRGB = {};  // rows 0..2 = rgb_w
    if (col < 3) aRGB = load_row8(rwg + (size_t)v * 96 + col * 32, k8, 32);

    // ---- bias C-fragments (row = Ti*16 + quad*4 + r) ----
    f4 cB0[2], cB1[2], cFB[2], cVB[2];
    #pragma unroll
    for (int Ti = 0; Ti < 2; Ti++) {
        #pragma unroll
        for (int r = 0; r < 4; r++) {
            int row = Ti * 16 + quad * 4 + r;
            cB0[Ti][r] = b0g[v * 32 + row];
            cB1[Ti][r] = b1g[v * 32 + row];
            cFB[Ti][r] = fbg[v * 32 + row];
            cVB[Ti][r] = vbg[v * 32 + row];
        }
    }
    const float rb0 = rbg[v * 3 + 0], rb1 = rbg[v * 3 + 1], rb2 = rbg[v * 3 + 2];
    const float sb  = sbg[v];
    const f4 z4 = {0.f, 0.f, 0.f, 0.f};

    for (int base = 0; base < c; base += 16) {
        const bool active = (base + col) < c;
        const int n = ncur;
        const float px = pxc, py = pyc, pz = pzc;
        const float dx = dxc, dy = dyc, dz = dzc;

        // prefetch next 16 points
        if (base + 16 < c) {
            int sl = min(base + 16 + col, c - 1);
            ncur = plist[v * CAP + sl];
            pxc = pts[3 * ncur]; pyc = pts[3 * ncur + 1]; pzc = pts[3 * ncur + 2];
            int ray = ncur >> 7;
            dxc = vds[3 * ray]; dyc = vds[3 * ray + 1]; dzc = vds[3 * ray + 2];
        }

        // ---- B-fragments: xyz encoding (63 dims + pad), per-lane 8 dims ----
        h8 bE0 = pack8(encdim(k8 + 0, 63, px, py, pz), encdim(k8 + 1, 63, px, py, pz),
                       encdim(k8 + 2, 63, px, py, pz), encdim(k8 + 3, 63, px, py, pz),
                       encdim(k8 + 4, 63, px, py, pz), encdim(k8 + 5, 63, px, py, pz),
                       encdim(k8 + 6, 63, px, py, pz), encdim(k8 + 7, 63, px, py, pz));
        h8 bE1 = pack8(encdim(32 + k8 + 0, 63, px, py, pz), encdim(32 + k8 + 1, 63, px, py, pz),
                       encdim(32 + k8 + 2, 63, px, py, pz), encdim(32 + k8 + 3, 63, px, py, pz),
                       encdim(32 + k8 + 4, 63, px, py, pz), encdim(32 + k8 + 5, 63, px, py, pz),
                       encdim(32 + k8 + 6, 63, px, py, pz), encdim(32 + k8 + 7, 63, px, py, pz));

        // ---- layer 0: h = relu(W0 ep + b0) ----
        f4 d0 = MF(aW0[0][0], bE0, cB0[0]); d0 = MF(aW0[0][1], bE1, d0);
        f4 d1 = MF(aW0[1][0], bE0, cB0[1]); d1 = MF(aW0[1][1], bE1, d1);
        d0 = relu4(d0); d1 = relu4(d1);
        h8 bH = makeB(d0, d1, quad, col);

        // ---- layer 1: g = relu(W1 h + b1) ----
        f4 e0 = MF(aW1[0], bH, cB1[0]);
        f4 e1 = MF(aW1[1], bH, cB1[1]);
        e0 = relu4(e0); e1 = relu4(e1);
        h8 bG = makeB(e0, e1, quad, col);

        // ---- sigma = sigma_w . g + sigma_b (row 0 of s) ----
        f4 s = MF(aSG, bG, z4);

        // ---- feat = FW g + fb (no relu) ----
        f4 f0 = MF(aFW[0], bG, cFB[0]);
        f4 f1 = MF(aFW[1], bG, cFB[1]);
        h8 bF = makeB(f0, f1, quad, col);

        // ---- dir encoding (27 dims + pad) as second k-chunk ----
        h8 bD = pack8(encdim(k8 + 0, 27, dx, dy, dz), encdim(k8 + 1, 27, dx, dy, dz),
                      encdim(k8 + 2, 27, dx, dy, dz), encdim(k8 + 3, 27, dx, dy, dz),
                      encdim(k8 + 4, 27, dx, dy, dz), encdim(k8 + 5, 27, dx, dy, dz),
                      encdim(k8 + 6, 27, dx, dy, dz), encdim(k8 + 7, 27, dx, dy, dz));

        // ---- view layer: h3 = relu(VW [feat, dirs] + vb) ----
        f4 v0 = MF(aVW[0][0], bF, cVB[0]); v0 = MF(aVW[0][1], bD, v0);
        f4 v1 = MF(aVW[1][0], bF, cVB[1]); v1 = MF(aVW[1][1], bD, v1);
        v0 = relu4(v0); v1 = relu4(v1);
        h8 bV = makeB(v0, v1, quad, col);

        // ---- rgb (rows 0..2) ----
        f4 o = MF(aRGB, bV, z4);

        if (quad == 0 && active) {
            out[3 * n + 0] = o[0] + rb0;
            out[3 * n + 1] = o[1] + rb1;
            out[3 * n + 2] = o[2] + rb2;
            out[3 * NPTS + n] = s[0] + sb;
        }
    }
}

extern "C" void kernel_launch(void* const* d_in, const int* in_sizes, int n_in,
                              void* d_out, int out_size, void* d_ws, size_t ws_size,
                              hipStream_t stream) {
    const float* pts = (const float*)d_in[0];
    const float* vds = (const float*)d_in[1];
    const float* w0  = (const float*)d_in[2];
    const float* b0  = (const float*)d_in[3];
    const float* w1  = (const float*)d_in[4];
    const float* b1  = (const float*)d_in[5];
    const float* fw  = (const float*)d_in[6];
    const float* fb  = (const float*)d_in[7];
    const float* sw  = (const float*)d_in[8];
    const float* sb  = (const float*)d_in[9];
    const float* vw  = (const float*)d_in[10];
    const float* vb  = (const float*)d_in[11];
    const float* rw  = (const float*)d_in[12];
    const float* rb  = (const float*)d_in[13];
    float* out = (float*)d_out;

    int* count = (int*)d_ws;
    int* plist = (int*)((char*)d_ws + NM * sizeof(int));

    (void)hipMemsetAsync(count, 0, NM * sizeof(int), stream);
    k_bucket<<<NPTS / 256, 256, 0, stream>>>(pts, count, plist);
    k_mlp<<<NM, 64, 0, stream>>>(pts, vds, w0, b0, w1, b1, fw, fb, sw, sb,
                                 vw, vb, rw, rb, count, plist, out);
}

// Round 9
// 167.766 us; speedup vs baseline: 1.8906x; 1.0900x over previous
//
#include <hip/hip_runtime.h>

#define NM    4096
#define NPTS  131072
#define CAP   128

typedef _Float16 h8 __attribute__((ext_vector_type(8)));
typedef _Float16 h2 __attribute__((ext_vector_type(2)));
typedef float    f4 __attribute__((ext_vector_type(4)));
typedef int      i4 __attribute__((ext_vector_type(4)));

#define MF(a, b, c) __builtin_amdgcn_mfma_f32_16x16x32_f16((a), (b), (c), 0, 0, 0)

#if __has_builtin(__builtin_amdgcn_global_load_lds)
#define USE_DMA 1
#else
#define USE_DMA 0
#endif

static __device__ inline h2 pk(float a, float b) {
    return __builtin_bit_cast(h2, __builtin_amdgcn_cvt_pkrtz(a, b));
}

static __device__ inline h8 pack8(float u0, float u1, float u2, float u3,
                                  float u4, float u5, float u6, float u7) {
    i4 t;
    t[0] = __builtin_bit_cast(int, pk(u0, u1));
    t[1] = __builtin_bit_cast(int, pk(u2, u3));
    t[2] = __builtin_bit_cast(int, pk(u4, u5));
    t[3] = __builtin_bit_cast(int, pk(u6, u7));
    return __builtin_bit_cast(h8, t);
}

// 8 guarded f16 from an fp32 row in LDS (reads unconditional + select).
static __device__ inline h8 lds_row8(const float* __restrict__ X, int base,
                                     int d0, int lim) {
    float u[8];
    #pragma unroll
    for (int jj = 0; jj < 8; jj++) {
        int d = d0 + jj;
        float raw = X[base + d];          // always in-bounds of X[3040]
        u[jj] = (d < lim) ? raw : 0.f;
    }
    return pack8(u[0], u[1], u[2], u[3], u[4], u[5], u[6], u[7]);
}

// aligned 8-float (32B) run in LDS -> h8 (two ds_read_b128)
static __device__ inline h8 lds_row8a(const float* __restrict__ X, int off) {
    f4 v0 = *(const f4*)(X + off);
    f4 v1 = *(const f4*)(X + off + 4);
    return pack8(v0[0], v0[1], v0[2], v0[3], v1[0], v1[1], v1[2], v1[3]);
}

// 8 guarded f16 from a global fp32 row (fallback staging path).
static __device__ inline h8 load_row8(const float* __restrict__ rb, int d0, int lim) {
    float u[8];
    #pragma unroll
    for (int jj = 0; jj < 8; jj++) {
        int d = d0 + jj;
        u[jj] = (d < lim) ? rb[d] : 0.f;
    }
    return pack8(u[0], u[1], u[2], u[3], u[4], u[5], u[6], u[7]);
}

// NeRF frequency-encoding dim d of (x,y,z); 0 for d >= lim.
static __device__ inline float encdim(int d, int lim, float x, float y, float z) {
    int tt = d - 3;
    int k  = tt / 6;
    int r  = tt - 6 * k;
    float p = x;
    p = (r == 1 || r == 4) ? y : p;
    p = (r == 2 || r == 5) ? z : p;
    float f   = __int_as_float((k + 127) << 23);   // 2^k
    float arg = p * f + ((r >= 3) ? 1.57079632679f : 0.f);  // cos = sin(+pi/2)
    float sv  = __sinf(arg);
    float raw = (d == 0) ? x : ((d == 1) ? y : z);
    float val = (d < 3) ? raw : sv;
    return (d < lim) ? val : 0.f;
}

// D-frag pair -> B-frag (verified in R8; see R8 notes for derivation).
static __device__ inline h8 makeB(f4 d0, f4 d1, int quad, int col) {
    int laneA = ((quad & 1) * 2) * 16 + col;
    int laneB = laneA + 16;
    float a0 = __shfl(d0[0], laneA), b0 = __shfl(d1[0], laneA);
    float a1 = __shfl(d0[1], laneA), b1 = __shfl(d1[1], laneA);
    float a2 = __shfl(d0[2], laneA), b2 = __shfl(d1[2], laneA);
    float a3 = __shfl(d0[3], laneA), b3 = __shfl(d1[3], laneA);
    float a4 = __shfl(d0[0], laneB), b4 = __shfl(d1[0], laneB);
    float a5 = __shfl(d0[1], laneB), b5 = __shfl(d1[1], laneB);
    float a6 = __shfl(d0[2], laneB), b6 = __shfl(d1[2], laneB);
    float a7 = __shfl(d0[3], laneB), b7 = __shfl(d1[3], laneB);
    bool hi = quad >= 2;
    return pack8(hi ? b0 : a0, hi ? b1 : a1, hi ? b2 : a2, hi ? b3 : a3,
                 hi ? b4 : a4, hi ? b5 : a5, hi ? b6 : a6, hi ? b7 : a7);
}

static __device__ inline f4 relu4(f4 a) {
    f4 r;
    r[0] = fmaxf(a[0], 0.f); r[1] = fmaxf(a[1], 0.f);
    r[2] = fmaxf(a[2], 0.f); r[3] = fmaxf(a[3], 0.f);
    return r;
}

#if USE_DMA
static __device__ inline void dma16(const float* g, const float* l) {
    __builtin_amdgcn_global_load_lds(
        (const __attribute__((address_space(1))) void*)g,
        (__attribute__((address_space(3))) void*)l, 16, 0, 0);
}
#endif

__global__ __launch_bounds__(256) void k_bucket(const float* __restrict__ pts,
                                                int* __restrict__ count,
                                                int* __restrict__ plist) {
    int n = blockIdx.x * 256 + threadIdx.x;
    if (n >= NPTS) return;
    float x = pts[3 * n + 0], y = pts[3 * n + 1], z = pts[3 * n + 2];
    int ix = (int)fminf(fmaxf(x * 16.f, 0.f), 15.f);
    int iy = (int)fminf(fmaxf(y * 16.f, 0.f), 15.f);
    int iz = (int)fminf(fmaxf(z * 16.f, 0.f), 15.f);
    int v = (ix << 8) | (iy << 4) | iz;
    int pos = atomicAdd(&count[v], 1);
    if (pos < CAP) plist[v * CAP + pos] = n;
}

// MFMA dataflow (R8, verified): weights as A-fragments in VGPRs, 16 points =
// MFMA columns per iter. Staging via 2-stage global_load_lds DMA into a
// 12.2 KB fp32 scratch (R8's per-lane scalar staging serialized ~26 fragment
// loads at HBM latency -> 13 us/wave). Plain __launch_bounds__(64): forcing
// min-waves spilled to scratch in R6 (254 MB HBM writes).
__global__ __launch_bounds__(64) void k_mlp(
    const float* __restrict__ pts, const float* __restrict__ vds,
    const float* __restrict__ w0g, const float* __restrict__ b0g,
    const float* __restrict__ w1g, const float* __restrict__ b1g,
    const float* __restrict__ fwg, const float* __restrict__ fbg,
    const float* __restrict__ swg, const float* __restrict__ sbg,
    const float* __restrict__ vwg, const float* __restrict__ vbg,
    const float* __restrict__ rwg, const float* __restrict__ rbg,
    const int* __restrict__ count, const int* __restrict__ plist,
    float* __restrict__ out) {
    __shared__ __align__(16) float X[3040];   // 12160 B, reused A/B stages

    const int v = blockIdx.x;
    const int t = threadIdx.x;
    const int c = min(count[v], CAP);
    if (c == 0) return;

    const int col  = t & 15;
    const int quad = t >> 4;
    const int k8   = quad * 8;

    // ---- stage A DMA: w0 (2016 f) at X[0], w1 (1024 f) at X[2016] ----
#if USE_DMA
    {
        const float* g = w0g + (size_t)v * 2016;
        #pragma unroll
        for (int k = 0; k < 7; k++) dma16(g + k * 256 + t * 4, X + k * 256);
        if (t < 56) dma16(g + 1792 + t * 4, X + 1792);
        g = w1g + (size_t)v * 1024;
        #pragma unroll
        for (int k = 0; k < 4; k++) dma16(g + k * 256 + t * 4, X + 2016 + k * 256);
    }
#endif

    // ---- first-iteration point prefetch + biases (overlap DMA drain) ----
    float pxc, pyc, pzc, dxc, dyc, dzc;
    int ncur;
    {
        int sl = min(col, c - 1);
        ncur = plist[v * CAP + sl];
        pxc = pts[3 * ncur]; pyc = pts[3 * ncur + 1]; pzc = pts[3 * ncur + 2];
        int ray = ncur >> 7;
        dxc = vds[3 * ray]; dyc = vds[3 * ray + 1]; dzc = vds[3 * ray + 2];
    }
    f4 cB0[2], cB1[2], cFB[2], cVB[2];
    #pragma unroll
    for (int Ti = 0; Ti < 2; Ti++) {
        #pragma unroll
        for (int r = 0; r < 4; r++) {
            int row = Ti * 16 + quad * 4 + r;
            cB0[Ti][r] = b0g[v * 32 + row];
            cB1[Ti][r] = b1g[v * 32 + row];
            cFB[Ti][r] = fbg[v * 32 + row];
            cVB[Ti][r] = vbg[v * 32 + row];
        }
    }
    const float rb0 = rbg[v * 3 + 0], rb1 = rbg[v * 3 + 1], rb2 = rbg[v * 3 + 2];
    const float sb  = sbg[v];

    h8 aW0[2][2], aVW[2][2], aW1[2], aFW[2], aSG, aRGB;

#if USE_DMA
    __syncthreads();   // drain stage-A DMA (1 wave: just waitcnt)

    // ---- unpack A: w0 rows (63-stride) + w1 (aligned) ----
    #pragma unroll
    for (int Ti = 0; Ti < 2; Ti++) {
        int rbase = (Ti * 16 + col) * 63;
        aW0[Ti][0] = lds_row8(X, rbase, k8, 63);
        aW0[Ti][1] = lds_row8(X, rbase, 32 + k8, 63);
        aW1[Ti] = lds_row8a(X, 2016 + (Ti * 16 + col) * 32 + k8);
    }
    __syncthreads();   // unpack-A reads drained before stage-B DMA overwrites X

    // ---- stage B DMA: vw(1888) @0, fw(1024) @1888, sw(32) @2912, rw(96) @2944 ----
    {
        const float* g = vwg + (size_t)v * 1888;
        #pragma unroll
        for (int k = 0; k < 7; k++) dma16(g + k * 256 + t * 4, X + k * 256);
        if (t < 24) dma16(g + 1792 + t * 4, X + 1792);
        g = fwg + (size_t)v * 1024;
        #pragma unroll
        for (int k = 0; k < 4; k++) dma16(g + k * 256 + t * 4, X + 1888 + k * 256);
        if (t < 8)  dma16(swg + (size_t)v * 32 + t * 4, X + 2912);
        if (t < 24) dma16(rwg + (size_t)v * 96 + t * 4, X + 2944);
    }
    __syncthreads();   // drain stage-B DMA

    // ---- unpack B ----
    #pragma unroll
    for (int Ti = 0; Ti < 2; Ti++) {
        int rbase = (Ti * 16 + col) * 59;
        aVW[Ti][0] = lds_row8(X, rbase, k8, 59);
        aVW[Ti][1] = lds_row8(X, rbase, 32 + k8, 59);
        aFW[Ti] = lds_row8a(X, 1888 + (Ti * 16 + col) * 32 + k8);
    }
    aSG = (col == 0) ? lds_row8a(X, 2912 + k8) : h8{};
    aRGB = (col < 3) ? lds_row8a(X, 2944 + col * 32 + k8) : h8{};
#else
    #pragma unroll
    for (int Ti = 0; Ti < 2; Ti++) {
        const float* rb = w0g + (size_t)v * 2016 + (Ti * 16 + col) * 63;
        aW0[Ti][0] = load_row8(rb, k8, 63);
        aW0[Ti][1] = load_row8(rb, 32 + k8, 63);
        rb = vwg + (size_t)v * 1888 + (Ti * 16 + col) * 59;
        aVW[Ti][0] = load_row8(rb, k8, 59);
        aVW[Ti][1] = load_row8(rb, 32 + k8, 59);
        aW1[Ti] = load_row8(w1g + (size_t)v * 1024 + (Ti * 16 + col) * 32, k8, 32);
        aFW[Ti] = load_row8(fwg + (size_t)v * 1024 + (Ti * 16 + col) * 32, k8, 32);
    }
    aSG = (col == 0) ? load_row8(swg + (size_t)v * 32, k8, 32) : h8{};
    aRGB = (col < 3) ? load_row8(rwg + (size_t)v * 96 + col * 32, k8, 32) : h8{};
#endif

    const f4 z4 = {0.f, 0.f, 0.f, 0.f};

    for (int base = 0; base < c; base += 16) {
        const bool active = (base + col) < c;
        const int n = ncur;
        const float px = pxc, py = pyc, pz = pzc;
        const float dx = dxc, dy = dyc, dz = dzc;

        if (base + 16 < c) {
            int sl = min(base + 16 + col, c - 1);
            ncur = plist[v * CAP + sl];
            pxc = pts[3 * ncur]; pyc = pts[3 * ncur + 1]; pzc = pts[3 * ncur + 2];
            int ray = ncur >> 7;
            dxc = vds[3 * ray]; dyc = vds[3 * ray + 1]; dzc = vds[3 * ray + 2];
        }

        h8 bE0 = pack8(encdim(k8 + 0, 63, px, py, pz), encdim(k8 + 1, 63, px, py, pz),
                       encdim(k8 + 2, 63, px, py, pz), encdim(k8 + 3, 63, px, py, pz),
                       encdim(k8 + 4, 63, px, py, pz), encdim(k8 + 5, 63, px, py, pz),
                       encdim(k8 + 6, 63, px, py, pz), encdim(k8 + 7, 63, px, py, pz));
        h8 bE1 = pack8(encdim(32 + k8 + 0, 63, px, py, pz), encdim(32 + k8 + 1, 63, px, py, pz),
                       encdim(32 + k8 + 2, 63, px, py, pz), encdim(32 + k8 + 3, 63, px, py, pz),
                       encdim(32 + k8 + 4, 63, px, py, pz), encdim(32 + k8 + 5, 63, px, py, pz),
                       encdim(32 + k8 + 6, 63, px, py, pz), encdim(32 + k8 + 7, 63, px, py, pz));

        // layer 0
        f4 d0 = MF(aW0[0][0], bE0, cB0[0]); d0 = MF(aW0[0][1], bE1, d0);
        f4 d1 = MF(aW0[1][0], bE0, cB0[1]); d1 = MF(aW0[1][1], bE1, d1);
        d0 = relu4(d0); d1 = relu4(d1);
        h8 bH = makeB(d0, d1, quad, col);

        // layer 1
        f4 e0 = MF(aW1[0], bH, cB1[0]);
        f4 e1 = MF(aW1[1], bH, cB1[1]);
        e0 = relu4(e0); e1 = relu4(e1);
        h8 bG = makeB(e0, e1, quad, col);

        // sigma
        f4 s = MF(aSG, bG, z4);

        // feature
        f4 f0 = MF(aFW[0], bG, cFB[0]);
        f4 f1 = MF(aFW[1], bG, cFB[1]);
        h8 bF = makeB(f0, f1, quad, col);

        // dir encoding
        h8 bD = pack8(encdim(k8 + 0, 27, dx, dy, dz), encdim(k8 + 1, 27, dx, dy, dz),
                      encdim(k8 + 2, 27, dx, dy, dz), encdim(k8 + 3, 27, dx, dy, dz),
                      encdim(k8 + 4, 27, dx, dy, dz), encdim(k8 + 5, 27, dx, dy, dz),
                      encdim(k8 + 6, 27, dx, dy, dz), encdim(k8 + 7, 27, dx, dy, dz));

        // view layer
        f4 v0 = MF(aVW[0][0], bF, cVB[0]); v0 = MF(aVW[0][1], bD, v0);
        f4 v1 = MF(aVW[1][0], bF, cVB[1]); v1 = MF(aVW[1][1], bD, v1);
        v0 = relu4(v0); v1 = relu4(v1);
        h8 bV = makeB(v0, v1, quad, col);

        // rgb
        f4 o = MF(aRGB, bV, z4);

        if (quad == 0 && active) {
            out[3 * n + 0] = o[0] + rb0;
            out[3 * n + 1] = o[1] + rb1;
            out[3 * n + 2] = o[2] + rb2;
            out[3 * NPTS + n] = s[0] + sb;
        }
    }
}

extern "C" void kernel_launch(void* const* d_in, const int* in_sizes, int n_in,
                              void* d_out, int out_size, void* d_ws, size_t ws_size,
                              hipStream_t stream) {
    const float* pts = (const float*)d_in[0];
    const float* vds = (const float*)d_in[1];
    const float* w0  = (const float*)d_in[2];
    const float* b0  = (const float*)d_in[3];
    const float* w1  = (const float*)d_in[4];
    const float* b1  = (const float*)d_in[5];
    const float* fw  = (const float*)d_in[6];
    const float* fb  = (const float*)d_in[7];
    const float* sw  = (const float*)d_in[8];
    const float* sb  = (const float*)d_in[9];
    const float* vw  = (const float*)d_in[10];
    const float* vb  = (const float*)d_in[11];
    const float* rw  = (const float*)d_in[12];
    const float* rb  = (const float*)d_in[13];
    float* out = (float*)d_out;

    int* count = (int*)d_ws;
    int* plist = (int*)((char*)d_ws + NM * sizeof(int));

    (void)hipMemsetAsync(count, 0, NM * sizeof(int), stream);
    k_bucket<<<NPTS / 256, 256, 0, stream>>>(pts, count, plist);
    k_mlp<<<NM, 64, 0, stream>>>(pts, vds, w0, b0, w1, b1, fw, fb, sw, sb,
                                 vw, vb, rw, rb, count, plist, out);
}